// Round 8
// baseline (505.378 us; speedup 1.0000x reference)
//
#include <hip/hip_runtime.h>
#include <hip/hip_bf16.h>

// GraphAttentionLayer on MI355X — rank-1 + monotone-LeakyReLU factorization.
// e[b,i,j] = LR(s1_i + s2_j); p_ij = max(A_i E_j, B_i F_j) with
//   A=exp(x-m), B=exp(a*x-m), x=s1+mx, m=max(x,a*x), E=exp(s2-mx), F=exp(a(s2-mx)).
// Branch A*E >= B*F <=> s2_j >= -s1_i (monotone in s2) => bucket j by s2 into
// 512 bins; for row i with threshold bin t: bins>t pure-E, bins<t pure-F, only
// bin t exact. O_i = A*SEsuf[t] + B*SFpre[t] + exact(bin t);  l_i likewise.
// k1: MFMA Wh (bf16, [j][f] + [f][j]) + s1,s2 + per-block min/max of s2.
// k2s: bins, bucketed j/row lists, scalar bin sums + suffix/prefix.
// k2b: per-bin vector sums Sum(E*Wh), Sum(F*Wh) (LDS-reduced, jhalf-split).
// k2c: suffix/prefix tables.  k3p: per-row combine + exact bin + ELU.

#define ALPHA 0.2f
#define NN 4096
#define FD 128
#define NB 512

typedef __attribute__((ext_vector_type(8))) short s8v;     // 8 x bf16 raw bits
typedef __attribute__((ext_vector_type(4))) float f4v;
typedef __attribute__((ext_vector_type(2))) float f2v;
typedef __attribute__((ext_vector_type(2))) unsigned int u2v;

__device__ __forceinline__ unsigned short f2bf(float x) {  // round-half-up
  return (unsigned short)((__float_as_uint(x) + 0x8000u) >> 16);
}
__device__ __forceinline__ float bf2f(unsigned short s) {
  return __uint_as_float(((unsigned)s) << 16);
}
__device__ __forceinline__ void gl2lds16(const void* g, void* l) {
  __builtin_amdgcn_global_load_lds(
      (const __attribute__((address_space(1))) unsigned int*)g,
      (__attribute__((address_space(3))) unsigned int*)l, 16, 0, 0);
}

// ---------------- K1: Wh (both layouts) + s1/s2 + block min/max ----------
// grid 256 x 256 (4 waves). b=blk>>6, j0=(blk&63)<<6. C[m=j][n=f].
__global__ __launch_bounds__(256, 4) void k1_gemm(
    const float* __restrict__ h, const float* __restrict__ W,
    const float* __restrict__ a,
    unsigned short* __restrict__ Whjf,      // [4][4096][128] bf16
    unsigned short* __restrict__ WhTf,      // [4][128][4096] bf16
    float* __restrict__ s1g, float* __restrict__ s2g,
    float* __restrict__ bmax, float* __restrict__ bmin)
{
  __shared__ __align__(16) unsigned char wls[32768];
  __shared__ float wmax[4], wmin[4];
  const int tid = threadIdx.x;
  const int b = blockIdx.x >> 6;
  const int j0 = (blockIdx.x & 63) << 6;

#pragma unroll
  for (int it = 0; it < 16; ++it) {          // W -> swizzled bf16 W^T in LDS
    int cidx = it * 256 + tid;
    int i = cidx >> 5;
    int f0 = (cidx & 31) << 2;
    f4v v = *(const f4v*)(W + (size_t)cidx * 4);
#pragma unroll
    for (int e = 0; e < 4; ++e) {
      int f = f0 + e;
      int byte = f * 256 + (((i >> 3) ^ (f & 15)) << 4) + ((i & 7) << 1);
      *(unsigned short*)(wls + byte) = f2bf(v[e]);
    }
  }
  __syncthreads();

  const int w = tid >> 6, lane = tid & 63;
  const int quad = lane >> 4, lcol = lane & 15;
  const int jrow = j0 + 16 * w + lcol;

  f4v acc[8];
#pragma unroll
  for (int nt = 0; nt < 8; ++nt) acc[nt] = (f4v){0.f, 0.f, 0.f, 0.f};

#pragma unroll
  for (int kk = 0; kk < 4; ++kk) {
    const float* hp = h + (((size_t)(b * NN + jrow)) << 7) + (kk << 5) + (quad << 3);
    f4v v0 = *(const f4v*)hp;
    f4v v1 = *(const f4v*)(hp + 4);
    s8v af;
#pragma unroll
    for (int e = 0; e < 4; ++e) { af[e] = (short)f2bf(v0[e]); af[4+e] = (short)f2bf(v1[e]); }
#pragma unroll
    for (int nt = 0; nt < 8; ++nt) {
      int f = 16 * nt + lcol;
      int slot = ((kk << 2) + quad) ^ (f & 15);
      s8v bfr = *(const s8v*)(wls + (f << 8) + (slot << 4));
      acc[nt] = __builtin_amdgcn_mfma_f32_16x16x32_bf16(af, bfr, acc[nt], 0, 0, 0);
    }
  }

  float s1v[4] = {0,0,0,0}, s2v[4] = {0,0,0,0};
#pragma unroll
  for (int nt = 0; nt < 8; ++nt) {
    float a1 = a[16 * nt + lcol];
    float a2 = a[128 + 16 * nt + lcol];
#pragma unroll
    for (int r = 0; r < 4; ++r) { s1v[r] += acc[nt][r] * a1; s2v[r] += acc[nt][r] * a2; }
  }
#pragma unroll
  for (int r = 0; r < 4; ++r)
#pragma unroll
    for (int d = 1; d < 16; d <<= 1) {
      s1v[r] += __shfl_xor(s1v[r], d, 64);
      s2v[r] += __shfl_xor(s2v[r], d, 64);
    }
  if (lcol == 0) {
    int jb = b * NN + j0 + 16 * w + (quad << 2);
    *(f4v*)(s1g + jb) = (f4v){s1v[0], s1v[1], s1v[2], s1v[3]};
    *(f4v*)(s2g + jb) = (f4v){s2v[0], s2v[1], s2v[2], s2v[3]};
  }

#pragma unroll
  for (int nt = 0; nt < 8; ++nt) {          // stores: [f][j] packed + [j][f] scalar
    int f = 16 * nt + lcol;
    unsigned short q0 = f2bf(acc[nt][0]), q1 = f2bf(acc[nt][1]);
    unsigned short q2 = f2bf(acc[nt][2]), q3 = f2bf(acc[nt][3]);
    int jb = j0 + 16 * w + (quad << 2);
    u2v pk;
    pk[0] = (unsigned)q0 | ((unsigned)q1 << 16);
    pk[1] = (unsigned)q2 | ((unsigned)q3 << 16);
    *(u2v*)(WhTf + ((size_t)(b * FD + f) << 12) + jb) = pk;
    Whjf[((size_t)(b * NN + jb + 0) << 7) + f] = q0;
    Whjf[((size_t)(b * NN + jb + 1) << 7) + f] = q1;
    Whjf[((size_t)(b * NN + jb + 2) << 7) + f] = q2;
    Whjf[((size_t)(b * NN + jb + 3) << 7) + f] = q3;
  }

  float mv = (lcol == 0) ? fmaxf(fmaxf(s2v[0], s2v[1]), fmaxf(s2v[2], s2v[3])) : -1e30f;
  float nv = (lcol == 0) ? fminf(fminf(s2v[0], s2v[1]), fminf(s2v[2], s2v[3])) : 1e30f;
#pragma unroll
  for (int d = 1; d < 64; d <<= 1) {
    mv = fmaxf(mv, __shfl_xor(mv, d, 64));
    nv = fminf(nv, __shfl_xor(nv, d, 64));
  }
  if (lane == 0) { wmax[w] = mv; wmin[w] = nv; }
  __syncthreads();
  if (tid == 0) {
    bmax[blockIdx.x] = fmaxf(fmaxf(wmax[0], wmax[1]), fmaxf(wmax[2], wmax[3]));
    bmin[blockIdx.x] = fminf(fminf(wmin[0], wmin[1]), fminf(wmin[2], wmin[3]));
  }
}

// ---------------- K2s: binning + bucket lists + scalar sums ----------------
__global__ __launch_bounds__(256) void k2s(
    const float* __restrict__ s1g, const float* __restrict__ s2g,
    const float* __restrict__ bmax, const float* __restrict__ bmin,
    float* __restrict__ gmeta, unsigned short* __restrict__ gbinj,
    unsigned short* __restrict__ gti, unsigned short* __restrict__ gjlist,
    unsigned short* __restrict__ growlist, unsigned int* __restrict__ gbinstart,
    float* __restrict__ gsEsuf, float* __restrict__ gsFpre)
{
  __shared__ unsigned int cnt[NB], cur[NB], rcnt[NB], rcur[NB];
  __shared__ float sE[NB], sF[NB];
  __shared__ unsigned int bst[NB + 1], rst[NB + 1];
  __shared__ unsigned char binL[NN], tiL[NN];
  __shared__ float smx, smn, sinv;  // note: bin fits u8? NB=512 -> use u16 LDS? see below
  __shared__ unsigned short binL2[NN], tiL2[NN];
  const int b = blockIdx.x, tid = threadIdx.x;
  (void)binL; (void)tiL;

  for (int v = tid; v < NB; v += 256) { cnt[v] = 0; rcnt[v] = 0; sE[v] = 0.f; sF[v] = 0.f; }
  __syncthreads();
  if (tid == 0) {
    float mx = bmax[b * 64], mn = bmin[b * 64];
    for (int t = 1; t < 64; ++t) {
      mx = fmaxf(mx, bmax[b * 64 + t]);
      mn = fminf(mn, bmin[b * 64 + t]);
    }
    smx = mx; smn = mn; sinv = (float)NB / fmaxf(mx - mn, 1e-20f);
    gmeta[b * 4] = mx; gmeta[b * 4 + 1] = mn; gmeta[b * 4 + 2] = sinv;
  }
  __syncthreads();
  const float mx = smx, mn = smn, inv = sinv;

  for (int jj = tid; jj < NN; jj += 256) {
    float s2 = s2g[b * NN + jj];
    int bin = (int)floorf((s2 - mn) * inv);
    bin = bin < 0 ? 0 : (bin > NB - 1 ? NB - 1 : bin);
    binL2[jj] = (unsigned short)bin;
    gbinj[b * NN + jj] = (unsigned short)bin;
    atomicAdd(&cnt[bin], 1u);
    atomicAdd(&sE[bin], __expf(s2 - mx));
    atomicAdd(&sF[bin], __expf(ALPHA * (s2 - mx)));
    float th = -s1g[b * NN + jj];
    int t = (int)floorf((th - mn) * inv);
    t = t < 0 ? 0 : (t > NB - 1 ? NB - 1 : t);
    tiL2[jj] = (unsigned short)t;
    gti[b * NN + jj] = (unsigned short)t;
    atomicAdd(&rcnt[t], 1u);
  }
  __syncthreads();
  if (tid == 0) {
    unsigned int acc = 0;
    for (int t = 0; t < NB; ++t) { bst[t] = acc; acc += cnt[t]; }
    bst[NB] = acc;
    acc = 0;
    for (int t = 0; t < NB; ++t) { rst[t] = acc; acc += rcnt[t]; }
    rst[NB] = acc;
    float ra = 0.f;
    for (int t = NB - 1; t >= 0; --t) { gsEsuf[b * NB + t] = ra; ra += sE[t]; }
    float fa = 0.f;
    for (int t = 0; t < NB; ++t) { gsFpre[b * NB + t] = fa; fa += sF[t]; }
  }
  __syncthreads();
  for (int v = tid; v < NB; v += 256) { cur[v] = bst[v]; rcur[v] = rst[v]; }
  for (int v = tid; v < NB + 1; v += 256) gbinstart[b * (NB + 1) + v] = bst[v];
  __syncthreads();
  for (int jj = tid; jj < NN; jj += 256) {
    int bin = binL2[jj];
    unsigned int pos = atomicAdd(&cur[bin], 1u);
    gjlist[b * NN + pos] = (unsigned short)jj;
    int t = tiL2[jj];
    unsigned int rp = atomicAdd(&rcur[t], 1u);
    growlist[b * NN + rp] = (unsigned short)jj;
  }
}

// ---------------- K2b: per-bin vector sums (jhalf-split partials) ----------
// grid 64: b=blk>>4, g=(blk>>1)&7 (16-ch group), jh=blk&1. 256 thr.
__global__ __launch_bounds__(256) void k2b(
    const unsigned short* __restrict__ WhTf, const float* __restrict__ s2g,
    const unsigned short* __restrict__ gbinj, const float* __restrict__ gmeta,
    float* __restrict__ gEWhp, float* __restrict__ gFWhp)
{
  __shared__ float lE[16][NB], lF[16][NB];   // 64 KB
  const int tid = threadIdx.x;
  const int b = blockIdx.x >> 4, g = (blockIdx.x >> 1) & 7, jh = blockIdx.x & 1;
  for (int v = tid; v < 16 * NB; v += 256) { ((float*)lE)[v] = 0.f; ((float*)lF)[v] = 0.f; }
  const float mx = gmeta[b * 4];
  const int j0 = jh * 2048 + tid * 8;
  float E8[8], F8[8]; int bin8[8];
#pragma unroll
  for (int e = 0; e < 8; ++e) {
    float s2 = s2g[b * NN + j0 + e];
    E8[e] = __expf(s2 - mx);
    F8[e] = __expf(ALPHA * (s2 - mx));
    bin8[e] = gbinj[b * NN + j0 + e];
  }
  __syncthreads();
  for (int ch = 0; ch < 16; ++ch) {
    int f = g * 16 + ch;
    s8v wh = *(const s8v*)(WhTf + ((size_t)(b * FD + f) << 12) + j0);
#pragma unroll
    for (int e = 0; e < 8; ++e) {
      float wv = bf2f((unsigned short)wh[e]);
      atomicAdd(&lE[ch][bin8[e]], E8[e] * wv);
      atomicAdd(&lF[ch][bin8[e]], F8[e] * wv);
    }
  }
  __syncthreads();
  for (int v = tid; v < 16 * NB; v += 256) {
    int ch = v >> 9, bin = v & (NB - 1);
    size_t o = (((size_t)jh * 4 + b) * NB + bin) * 128 + g * 16 + ch;
    gEWhp[o] = lE[ch][bin];
    gFWhp[o] = lF[ch][bin];
  }
}

// ---------------- K2c: suffix/prefix tables ----------------
__global__ __launch_bounds__(256) void k2c(
    const float* __restrict__ gEWhp, const float* __restrict__ gFWhp,
    float* __restrict__ gSEsuf, float* __restrict__ gSFpre)
{
  const int b = blockIdx.x, tid = threadIdx.x;
  if (tid < 128) {
    const int ch = tid; float r = 0.f;
    for (int t = NB - 1; t >= 0; --t) {
      gSEsuf[((size_t)b * NB + t) * 128 + ch] = r;
      r += gEWhp[((size_t)b * NB + t) * 128 + ch] +
           gEWhp[(((size_t)4 + b) * NB + t) * 128 + ch];
    }
  } else {
    const int ch = tid - 128; float r = 0.f;
    for (int t = 0; t < NB; ++t) {
      gSFpre[((size_t)b * NB + t) * 128 + ch] = r;
      r += gFWhp[((size_t)b * NB + t) * 128 + ch] +
           gFWhp[(((size_t)4 + b) * NB + t) * 128 + ch];
    }
  }
}

// ---------------- K3p: per-row combine + exact bin + ELU ----------------
// grid 64 x 512 (8 waves): b=blk>>4, slice=blk&15; wave: 32 rows; lane: 2 ch.
__global__ __launch_bounds__(512) void k3p(
    const unsigned short* __restrict__ Whjf, const float* __restrict__ s1g,
    const float* __restrict__ s2g, const unsigned short* __restrict__ gti,
    const unsigned short* __restrict__ growlist,
    const unsigned short* __restrict__ gjlist,
    const unsigned int* __restrict__ gbinstart,
    const float* __restrict__ gsEsuf, const float* __restrict__ gsFpre,
    const float* __restrict__ gSEsuf, const float* __restrict__ gSFpre,
    const float* __restrict__ gmeta, float* __restrict__ out)
{
  const int tid = threadIdx.x, wv = tid >> 6, lane = tid & 63;
  const int b = blockIdx.x >> 4, sl = blockIdx.x & 15;
  const float mx = gmeta[b * 4];
  const int ch = lane * 2;

  for (int rr = 0; rr < 32; ++rr) {
    int idx = sl * 256 + wv * 32 + rr;
    int i = growlist[b * NN + idx];
    float s1 = s1g[b * NN + i];
    int t = gti[b * NN + i];
    float x = s1 + mx;
    float m = fmaxf(x, ALPHA * x);
    float A = __expf(x - m), Bq = __expf(ALPHA * x - m);
    const float* SE = gSEsuf + ((size_t)b * NB + t) * 128;
    const float* SF = gSFpre + ((size_t)b * NB + t) * 128;
    float a0 = A * SE[ch] + Bq * SF[ch];
    float a1 = A * SE[ch + 1] + Bq * SF[ch + 1];
    float l = A * gsEsuf[b * NB + t] + Bq * gsFpre[b * NB + t];
    unsigned int m0 = gbinstart[b * (NB + 1) + t];
    unsigned int m1 = gbinstart[b * (NB + 1) + t + 1];
    for (unsigned int k = m0; k < m1; ++k) {
      int j = gjlist[b * NN + k];
      float s2 = s2g[b * NN + j];
      float p = fmaxf(A * __expf(s2 - mx), Bq * __expf(ALPHA * (s2 - mx)));
      l += p;
      unsigned int w2 = *(const unsigned int*)(Whjf + ((size_t)(b * NN + j) << 7) + ch);
      a0 += p * __uint_as_float(w2 << 16);
      a1 += p * __uint_as_float(w2 & 0xFFFF0000u);
    }
    float il = 1.0f / l;
    float o0 = a0 * il, o1 = a1 * il;
    o0 = o0 > 0.f ? o0 : (__expf(o0) - 1.f);
    o1 = o1 > 0.f ? o1 : (__expf(o1) - 1.f);
    *(f2v*)(out + ((size_t)(b * NN + i) << 7) + ch) = (f2v){o0, o1};
  }
}

extern "C" void kernel_launch(void* const* d_in, const int* in_sizes, int n_in,
                              void* d_out, int out_size, void* d_ws, size_t ws_size,
                              hipStream_t stream) {
  const float* h = (const float*)d_in[0];
  const float* W = (const float*)d_in[1];
  const float* a = (const float*)d_in[2];
  float* out = (float*)d_out;
  unsigned char* ws = (unsigned char*)d_ws;

  unsigned short* Whjf = (unsigned short*)ws;                    // 4 MB
  unsigned short* WhTf = (unsigned short*)(ws + 4194304);        // 4 MB
  float* s1g = (float*)(ws + 8388608);                           // 64 KB
  float* s2g = (float*)(ws + 8454144);                           // 64 KB
  float* bmx = (float*)(ws + 8519680);                           // 1 KB
  float* bmn = (float*)(ws + 8520704);                           // 1 KB
  float* gmeta = (float*)(ws + 8521728);                         // 256 B
  unsigned short* gbinj = (unsigned short*)(ws + 8521984);       // 32 KB
  unsigned short* gti = (unsigned short*)(ws + 8554752);         // 32 KB
  unsigned short* gjlist = (unsigned short*)(ws + 8587520);      // 32 KB
  unsigned short* growlist = (unsigned short*)(ws + 8620288);    // 32 KB
  unsigned int* gbinstart = (unsigned int*)(ws + 8653056);       // 8.4 KB
  float* gsEsuf = (float*)(ws + 8661504);                        // 8 KB
  float* gsFpre = (float*)(ws + 8669696);                        // 8 KB
  float* gEWhp = (float*)(ws + 8677888);                         // 2 MB
  float* gFWhp = (float*)(ws + 10775040);                        // 2 MB
  float* gSEsuf = (float*)(ws + 12872192);                       // 1 MB
  float* gSFpre = (float*)(ws + 13920768);                       // 1 MB
  const size_t NEEDED = 14969344;
  if (ws_size < NEEDED) return;  // clean absmax-fail => ws too small

  hipLaunchKernelGGL(k1_gemm, dim3(256), dim3(256), 0, stream,
                     h, W, a, Whjf, WhTf, s1g, s2g, bmx, bmn);
  hipLaunchKernelGGL(k2s, dim3(4), dim3(256), 0, stream,
                     s1g, s2g, bmx, bmn, gmeta, gbinj, gti, gjlist, growlist,
                     gbinstart, gsEsuf, gsFpre);
  hipLaunchKernelGGL(k2b, dim3(64), dim3(256), 0, stream,
                     WhTf, s2g, gbinj, gmeta, gEWhp, gFWhp);
  hipLaunchKernelGGL(k2c, dim3(4), dim3(256), 0, stream,
                     gEWhp, gFWhp, gSEsuf, gSFpre);
  hipLaunchKernelGGL(k3p, dim3(64), dim3(512), 0, stream,
                     Whjf, s1g, s2g, gti, growlist, gjlist, gbinstart,
                     gsEsuf, gsFpre, gSEsuf, gSFpre, gmeta, out);
}

// Round 9
// 141.330 us; speedup vs baseline: 3.5759x; 3.5759x over previous
//
#include <hip/hip_runtime.h>
#include <hip/hip_bf16.h>

// GraphAttentionLayer on MI355X. fp32 I/O, bf16 MFMA internally.
// e = LR(s1_i + s2_j), softmax_j, out = elu(attn @ Wh).
// Scale-free scores (row factor cancels in softmax):
//   q_ij = max(E_j, r_i*F_j); E = exp(s2-8), F = exp(ALPHA*(s2-8)),
//   r_i = exp((ALPHA-1)*(s1_i+8));  O_i = sum_j q Wh / sum_j q.
// K1: Wh MFMA -> tiled WhT [b][c:16][oct:32][f:128][jo:8] bf16 + s1,E,F.
// K3-split: 256 blocks = 4b x 8 row-groups(512 rows) x 8 j-eighths(512 j).
//   8 waves/block own disjoint 64-row tiles, SHARE the j-slice reads (L1
//   multicast, barrier-synced) -> per-CU distinct reads 128 KB (8x less).
//   Writes bf16 partial O + f32 partial l. K4: 8-way combine + ELU.
// Fallback: if ws too small for partials, launch R7's monolithic k3.

#define ALPHA 0.2f
#define NN 4096
#define FD 128

typedef __attribute__((ext_vector_type(8))) short s8v;     // 8 x bf16 raw bits
typedef __attribute__((ext_vector_type(4))) float f4v;
typedef __attribute__((ext_vector_type(2))) unsigned int u2v;
typedef __attribute__((ext_vector_type(4))) unsigned int u4v;

__device__ __forceinline__ unsigned short f2bf(float x) {  // round-half-up
  return (unsigned short)((__float_as_uint(x) + 0x8000u) >> 16);
}
__device__ __forceinline__ float bf2f(unsigned short s) {
  return __uint_as_float(((unsigned)s) << 16);
}

// ---------------- K1: Wh + tiled WhT + s1/E/F (R7, unchanged) ----------------
__global__ __launch_bounds__(256, 4) void k1_gemm(
    const float* __restrict__ h, const float* __restrict__ W,
    const float* __restrict__ a,
    unsigned short* __restrict__ WhTt,      // tiled [4][16][32][128][8] bf16
    float* __restrict__ s1g, float* __restrict__ Eg, float* __restrict__ Fg)
{
  __shared__ __align__(16) unsigned char wls[32768];
  const int tid = threadIdx.x;
  const int b = blockIdx.x >> 6;
  const int j0 = (blockIdx.x & 63) << 6;

#pragma unroll
  for (int it = 0; it < 16; ++it) {          // W -> swizzled bf16 W^T in LDS
    int cidx = it * 256 + tid;
    int i = cidx >> 5;
    int f0 = (cidx & 31) << 2;
    f4v v = *(const f4v*)(W + (size_t)cidx * 4);
#pragma unroll
    for (int e = 0; e < 4; ++e) {
      int f = f0 + e;
      int byte = f * 256 + (((i >> 3) ^ (f & 15)) << 4) + ((i & 7) << 1);
      *(unsigned short*)(wls + byte) = f2bf(v[e]);
    }
  }
  __syncthreads();

  const int w = tid >> 6, lane = tid & 63;
  const int quad = lane >> 4, lcol = lane & 15;
  const int jrow = j0 + 16 * w + lcol;

  f4v acc[8];
#pragma unroll
  for (int nt = 0; nt < 8; ++nt) acc[nt] = (f4v){0.f, 0.f, 0.f, 0.f};

#pragma unroll
  for (int kk = 0; kk < 4; ++kk) {
    const float* hp = h + (((size_t)(b * NN + jrow)) << 7) + (kk << 5) + (quad << 3);
    f4v v0 = *(const f4v*)hp;
    f4v v1 = *(const f4v*)(hp + 4);
    s8v af;
#pragma unroll
    for (int e = 0; e < 4; ++e) { af[e] = (short)f2bf(v0[e]); af[4+e] = (short)f2bf(v1[e]); }
#pragma unroll
    for (int nt = 0; nt < 8; ++nt) {
      int f = 16 * nt + lcol;
      int slot = ((kk << 2) + quad) ^ (f & 15);
      s8v bfr = *(const s8v*)(wls + (f << 8) + (slot << 4));
      acc[nt] = __builtin_amdgcn_mfma_f32_16x16x32_bf16(af, bfr, acc[nt], 0, 0, 0);
    }
  }

  float s1v[4] = {0,0,0,0}, s2v[4] = {0,0,0,0};
#pragma unroll
  for (int nt = 0; nt < 8; ++nt) {
    float a1 = a[16 * nt + lcol];
    float a2 = a[128 + 16 * nt + lcol];
#pragma unroll
    for (int r = 0; r < 4; ++r) { s1v[r] += acc[nt][r] * a1; s2v[r] += acc[nt][r] * a2; }
  }
#pragma unroll
  for (int r = 0; r < 4; ++r)
#pragma unroll
    for (int d = 1; d < 16; d <<= 1) {
      s1v[r] += __shfl_xor(s1v[r], d, 64);
      s2v[r] += __shfl_xor(s2v[r], d, 64);
    }
  if (lcol == 0) {
    int jb = b * NN + j0 + 16 * w + (quad << 2);
    *(f4v*)(s1g + jb) = (f4v){s1v[0], s1v[1], s1v[2], s1v[3]};
    f4v Ee, Ff;
#pragma unroll
    for (int r = 0; r < 4; ++r) {
      float d = s2v[r] - 8.0f;              // <= 0 given |s2| <= 8
      Ee[r] = __expf(d);
      Ff[r] = __expf(ALPHA * d);
    }
    *(f4v*)(Eg + jb) = Ee;
    *(f4v*)(Fg + jb) = Ff;
  }

  {
    const int c = j0 >> 8;
    const int octb = ((j0 & 255) >> 3) + 2 * w + (quad >> 1);
    const int eoff = (quad & 1) << 2;
#pragma unroll
    for (int nt = 0; nt < 8; ++nt) {
      int f = 16 * nt + lcol;
      unsigned u0 = __float_as_uint(acc[nt][0]) + 0x8000u;
      unsigned u1 = __float_as_uint(acc[nt][1]) + 0x8000u;
      unsigned u2 = __float_as_uint(acc[nt][2]) + 0x8000u;
      unsigned u3 = __float_as_uint(acc[nt][3]) + 0x8000u;
      u2v pk;
      pk[0] = (u0 >> 16) | (u1 & 0xFFFF0000u);
      pk[1] = (u2 >> 16) | (u3 & 0xFFFF0000u);
      size_t off = ((((size_t)(b * 16 + c) * 32 + octb) * 128 + f) << 3) + eoff;
      *(u2v*)(WhTt + off) = pk;
    }
  }
}

// ---------------- K3-split: partial P@Wh over a 512-j eighth ----------------
// grid 256 x 512 thr. blk: b=blk>>6, rg=(blk>>3)&7, jq=blk&7. Wave w owns
// rows [rg*512 + w*64, +64) (mt=4); all waves share the j-slice reads.
__global__ __launch_bounds__(512, 2) void k3_split(
    const unsigned short* __restrict__ WhTt,
    const float* __restrict__ s1g,
    const float* __restrict__ Eg,
    const float* __restrict__ Fg,
    unsigned short* __restrict__ pO,        // [256][512][128] bf16 partial O
    float* __restrict__ pl)                 // [256][512] f32 partial l
{
  const int tid = threadIdx.x;
  const int w = tid >> 6, lane = tid & 63;
  const int quad = lane >> 4, lcol = lane & 15;
  const int blk = blockIdx.x;
  const int b = blk >> 6, rg = (blk >> 3) & 7, jq = blk & 7;
  const int irow0 = rg * 512 + w * 64;

  float rr[4];
#pragma unroll
  for (int mt = 0; mt < 4; ++mt) {
    float x = s1g[b * NN + irow0 + 16 * mt + lcol] + 8.0f;
    rr[mt] = __expf((ALPHA - 1.0f) * x);    // <= 1 (x >= 0)
  }

  f4v acc[4][8], accL[4];
#pragma unroll
  for (int mt = 0; mt < 4; ++mt) {
    accL[mt] = (f4v){0.f, 0.f, 0.f, 0.f};
#pragma unroll
    for (int nt = 0; nt < 8; ++nt) acc[mt][nt] = (f4v){0.f, 0.f, 0.f, 0.f};
  }
  s8v ones;
  {
    short o = (lcol == 0) ? (short)0x3F80 : (short)0;
#pragma unroll
    for (int t = 0; t < 8; ++t) ones[t] = o;
  }

  const unsigned short* whtb = WhTt + ((size_t)b << 19);
  const float* Egb = Eg + b * NN;
  const float* Fgb = Fg + b * NN;
  const int j0 = jq << 9;                   // 512-j window

  for (int sg = 0; sg < 4; ++sg) {          // 16 ksteps, barrier every 4
#pragma unroll
    for (int si = 0; si < 4; ++si) {
      const int s = (sg << 2) + si;
      const int jbase = j0 + (s << 5) + (quad << 3);
      const int og = jbase >> 3;            // global j-octet
      const unsigned short* tile =
          whtb + (((size_t)(og >> 5)) << 15) + ((og & 31) << 10);
      s8v bfr[8];
#pragma unroll
      for (int nt = 0; nt < 8; ++nt)
        bfr[nt] = *(const s8v*)(tile + (((nt << 4) + lcol) << 3));
      f4v Ea0 = *(const f4v*)(Egb + jbase);
      f4v Ea1 = *(const f4v*)(Egb + jbase + 4);
      f4v Fa0 = *(const f4v*)(Fgb + jbase);
      f4v Fa1 = *(const f4v*)(Fgb + jbase + 4);
      float Ev[8] = {Ea0[0], Ea0[1], Ea0[2], Ea0[3], Ea1[0], Ea1[1], Ea1[2], Ea1[3]};
      float Fv[8] = {Fa0[0], Fa0[1], Fa0[2], Fa0[3], Fa1[0], Fa1[1], Fa1[2], Fa1[3]};

      s8v af[4];
#pragma unroll
      for (int mt = 0; mt < 4; ++mt) {      // q = max(E, r*F), A-frag layout
        float R = rr[mt];
        u4v pk4;
#pragma unroll
        for (int t = 0; t < 8; t += 2) {
          float q0 = fmaxf(Ev[t], R * Fv[t]);
          float q1 = fmaxf(Ev[t + 1], R * Fv[t + 1]);
          unsigned u0 = __float_as_uint(q0) + 0x8000u;
          unsigned u1 = __float_as_uint(q1) + 0x8000u;
          pk4[t >> 1] = __builtin_amdgcn_perm(u1, u0, 0x07060302);
        }
        af[mt] = __builtin_bit_cast(s8v, pk4);
      }
#pragma unroll
      for (int nt = 0; nt < 8; ++nt)
#pragma unroll
        for (int mt = 0; mt < 4; ++mt)
          acc[mt][nt] = __builtin_amdgcn_mfma_f32_16x16x32_bf16(af[mt], bfr[nt], acc[mt][nt], 0, 0, 0);
#pragma unroll
      for (int mt = 0; mt < 4; ++mt)
        accL[mt] = __builtin_amdgcn_mfma_f32_16x16x32_bf16(af[mt], ones, accL[mt], 0, 0, 0);
    }
    __syncthreads();                        // keep waves in L1 reuse window
  }

  // partial stores (rows exclusive per wave -> no reduction needed)
  unsigned short* po = pO + (size_t)blk * 65536;
#pragma unroll
  for (int mt = 0; mt < 4; ++mt) {
    if (lcol == 0) {
#pragma unroll
      for (int r = 0; r < 4; ++r)
        pl[(size_t)blk * 512 + w * 64 + 16 * mt + (quad << 2) + r] = accL[mt][r];
    }
#pragma unroll
    for (int nt = 0; nt < 8; ++nt)
#pragma unroll
      for (int r = 0; r < 4; ++r) {
        int row = w * 64 + 16 * mt + (quad << 2) + r;
        po[(row << 7) + (nt << 4) + lcol] = f2bf(acc[mt][nt][r]);
      }
  }
}

// ---------------- K4: 8-way combine + softmax normalize + ELU ----------------
// grid 256 x 256 thr: blk: b=blk>>6, rg=(blk>>3)&7, rsl=blk&7 (64 rows).
__global__ __launch_bounds__(256) void k4_comb(
    const unsigned short* __restrict__ pO, const float* __restrict__ pl,
    float* __restrict__ out)
{
  const int tid = threadIdx.x, blk = blockIdx.x;
  const int b = blk >> 6, rg = (blk >> 3) & 7, rsl = blk & 7;
  const int row_loc = rsl * 64 + (tid >> 2);
  const int fb = (tid & 3) << 5;
  const int base = (b << 6) | (rg << 3);

  float l = 0.f;
#pragma unroll
  for (int q = 0; q < 8; ++q) l += pl[(size_t)(base + q) * 512 + row_loc];
  float il = 1.0f / l;

  size_t orow = (((size_t)b * NN + rg * 512 + row_loc) << 7);
#pragma unroll
  for (int g = 0; g < 4; ++g) {
    int f = fb + (g << 3);
    float s[8] = {0.f, 0.f, 0.f, 0.f, 0.f, 0.f, 0.f, 0.f};
#pragma unroll
    for (int q = 0; q < 8; ++q) {
      u4v pk = *(const u4v*)(pO + (size_t)(base + q) * 65536 + (row_loc << 7) + f);
      const unsigned short* us = (const unsigned short*)&pk;
#pragma unroll
      for (int e = 0; e < 8; ++e) s[e] += bf2f(us[e]);
    }
    f4v o0, o1;
#pragma unroll
    for (int e = 0; e < 4; ++e) {
      float v = s[e] * il;
      o0[e] = v > 0.f ? v : (__expf(v) - 1.f);
    }
#pragma unroll
    for (int e = 0; e < 4; ++e) {
      float v = s[4 + e] * il;
      o1[e] = v > 0.f ? v : (__expf(v) - 1.f);
    }
    *(f4v*)(out + orow + f) = o0;
    *(f4v*)(out + orow + f + 4) = o1;
  }
}

// ---------------- K3-mono (R7 fallback, verbatim) ----------------
__global__ __launch_bounds__(512, 2) void k3_mono(
    const unsigned short* __restrict__ WhTt,
    const float* __restrict__ s1g,
    const float* __restrict__ Eg,
    const float* __restrict__ Fg,
    float* __restrict__ out)
{
  __shared__ __align__(16) unsigned char smem[33024];
  const int tid = threadIdx.x;
  const int kp = tid >> 6, lane = tid & 63;
  const int quad = lane >> 4, lcol = lane & 15;
  const int b = (blockIdx.x & 7) >> 1;
  const int i0 = ((((blockIdx.x & 1) << 5) | (blockIdx.x >> 3))) << 6;
  const int c0 = (blockIdx.x >> 3) & 15;
  const int oct = (kp << 2) + quad;

  float Ar[4], Br[4];
#pragma unroll
  for (int mt = 0; mt < 4; ++mt) {
    float x = s1g[b * NN + i0 + 16 * mt + lcol] + 8.0f;
    float m = fmaxf(x, ALPHA * x);
    Ar[mt] = __expf(x - m);
    Br[mt] = __expf(ALPHA * x - m);
  }

  f4v acc[4][8], accL[4];
#pragma unroll
  for (int mt = 0; mt < 4; ++mt) {
    accL[mt] = (f4v){0.f, 0.f, 0.f, 0.f};
#pragma unroll
    for (int nt = 0; nt < 8; ++nt) acc[mt][nt] = (f4v){0.f, 0.f, 0.f, 0.f};
  }
  s8v ones;
  {
    short o = (lcol == 0) ? (short)0x3F80 : (short)0;
#pragma unroll
    for (int t = 0; t < 8; ++t) ones[t] = o;
  }

  const unsigned short* whtb = WhTt + ((size_t)b << 19);
  const float* Egb = Eg + b * NN;
  const float* Fgb = Fg + b * NN;
  const int jw = oct << 3;

  f4v Ec0 = *(const f4v*)(Egb + (c0 << 8) + jw);
  f4v Ec1 = *(const f4v*)(Egb + (c0 << 8) + jw + 4);
  f4v Fc0 = *(const f4v*)(Fgb + (c0 << 8) + jw);
  f4v Fc1 = *(const f4v*)(Fgb + (c0 << 8) + jw + 4);

  for (int cc = 0; cc < 16; ++cc) {
    const int c = (cc + c0) & 15;
    const unsigned short* tile = whtb + ((size_t)c << 15) + (oct << 10);
    s8v bfr[8];
#pragma unroll
    for (int nt = 0; nt < 8; ++nt)
      bfr[nt] = *(const s8v*)(tile + (((nt << 4) + lcol) << 3));

    f4v En0, En1, Fn0, Fn1;
    if (cc < 15) {
      int jg = (((cc + 1 + c0) & 15) << 8) + jw;
      En0 = *(const f4v*)(Egb + jg); En1 = *(const f4v*)(Egb + jg + 4);
      Fn0 = *(const f4v*)(Fgb + jg); Fn1 = *(const f4v*)(Fgb + jg + 4);
    }

    float Ev[8] = {Ec0[0], Ec0[1], Ec0[2], Ec0[3], Ec1[0], Ec1[1], Ec1[2], Ec1[3]};
    float Fv[8] = {Fc0[0], Fc0[1], Fc0[2], Fc0[3], Fc1[0], Fc1[1], Fc1[2], Fc1[3]};

    s8v af[4];
#pragma unroll
    for (int mt = 0; mt < 4; ++mt) {
      float A = Ar[mt], Bc = Br[mt];
      u4v pk4;
#pragma unroll
      for (int t = 0; t < 8; t += 2) {
        float p0 = fmaxf(A * Ev[t], Bc * Fv[t]);
        float p1 = fmaxf(A * Ev[t + 1], Bc * Fv[t + 1]);
        unsigned u0 = __float_as_uint(p0) + 0x8000u;
        unsigned u1 = __float_as_uint(p1) + 0x8000u;
        pk4[t >> 1] = __builtin_amdgcn_perm(u1, u0, 0x07060302);
      }
      af[mt] = __builtin_bit_cast(s8v, pk4);
    }
#pragma unroll
    for (int nt = 0; nt < 8; ++nt)
#pragma unroll
      for (int mt = 0; mt < 4; ++mt)
        acc[mt][nt] = __builtin_amdgcn_mfma_f32_16x16x32_bf16(af[mt], bfr[nt], acc[mt][nt], 0, 0, 0);
#pragma unroll
    for (int mt = 0; mt < 4; ++mt)
      accL[mt] = __builtin_amdgcn_mfma_f32_16x16x32_bf16(af[mt], ones, accL[mt], 0, 0, 0);

    Ec0 = En0; Ec1 = En1; Fc0 = Fn0; Fc1 = Fn1;
  }

  float* hsum = (float*)smem;
  float* l_red = (float*)(smem + 32768);
#pragma unroll
  for (int t = 0; t < 4; ++t)
    *(f4v*)(hsum + tid * 16 + t * 4) = (f4v){0.f, 0.f, 0.f, 0.f};
  if (tid < 64) l_red[tid] = 0.f;
  __syncthreads();

#pragma unroll
  for (int mt = 0; mt < 4; ++mt) {
    if (lcol == 0) {
#pragma unroll
      for (int r = 0; r < 4; ++r)
        atomicAdd(&l_red[16 * mt + (quad << 2) + r], accL[mt][r]);
    }
#pragma unroll
    for (int nt = 0; nt < 8; ++nt)
#pragma unroll
      for (int r = 0; r < 4; ++r) {
        int row = 16 * mt + (quad << 2) + r;
        int f = (nt << 4) + lcol;
        int fx = (f + (quad << 3)) & 127;
        atomicAdd(&hsum[(row << 7) + fx], acc[mt][nt][r]);
      }
  }
  __syncthreads();

  {
    int r = tid >> 3;
    int f0 = (tid & 7) << 4;
    int off = ((r >> 2) & 3) << 3;
    float il = 1.0f / l_red[r];
    size_t o = (((size_t)b * NN + i0 + r) << 7) + f0;
#pragma unroll
    for (int t = 0; t < 4; ++t) {
      int fx = (f0 + 4 * t + off) & 127;
      f4v v = *(const f4v*)(hsum + (r << 7) + fx);
      f4v ov;
#pragma unroll
      for (int e = 0; e < 4; ++e) {
        float x = v[e] * il;
        ov[e] = x > 0.f ? x : (__expf(x) - 1.f);
      }
      *(f4v*)(out + o + 4 * t) = ov;
    }
  }
}

extern "C" void kernel_launch(void* const* d_in, const int* in_sizes, int n_in,
                              void* d_out, int out_size, void* d_ws, size_t ws_size,
                              hipStream_t stream) {
  const float* h = (const float*)d_in[0];
  const float* W = (const float*)d_in[1];
  const float* a = (const float*)d_in[2];
  float* out = (float*)d_out;
  unsigned char* ws = (unsigned char*)d_ws;

  unsigned short* WhTt = (unsigned short*)ws;             // 4 MB tiled bf16
  float* s1g = (float*)(ws + 4194304);                    // 64 KB
  float* Eg  = (float*)(ws + 4259840);                    // 64 KB
  float* Fg  = (float*)(ws + 4325376);                    // 64 KB
  unsigned short* pO = (unsigned short*)(ws + 4390912);   // 32 MB bf16
  float* pl = (float*)(ws + 37945344);                    // 512 KB
  const size_t NEED_SPLIT = 38469632;
  const size_t NEED_MONO = 4390912;
  if (ws_size < NEED_MONO) return;  // clean absmax-fail => ws too small

  hipLaunchKernelGGL(k1_gemm, dim3(256), dim3(256), 0, stream,
                     h, W, a, WhTt, s1g, Eg, Fg);
  if (ws_size >= NEED_SPLIT) {
    hipLaunchKernelGGL(k3_split, dim3(256), dim3(512), 0, stream,
                       WhTt, s1g, Eg, Fg, pO, pl);
    hipLaunchKernelGGL(k4_comb, dim3(256), dim3(256), 0, stream,
                       pO, pl, out);
  } else {
    hipLaunchKernelGGL(k3_mono, dim3(256), dim3(512), 0, stream,
                       WhTt, s1g, Eg, Fg, out);
  }
}

// Round 10
// 132.806 us; speedup vs baseline: 3.8054x; 1.0642x over previous
//
#include <hip/hip_runtime.h>
#include <hip/hip_bf16.h>

// GraphAttentionLayer on MI355X. fp32 I/O, bf16 MFMA internally.
// e = LR(s1_i + s2_j), softmax_j, out = elu(attn @ Wh).
// Scale-free scores (row factor cancels in softmax):
//   q_ij = max(E_j, r_i*F_j); E = exp(s2-8), F = exp(ALPHA*(s2-8)),
//   r_i = exp((ALPHA-1)*(s1_i+8));  O_i = sum_j q Wh / sum_j q.
// K1: Wh MFMA -> tiled WhT [b][c:16][oct:32][f:128][jo:8] bf16 + s1,E,F.
// K3-split: 256 blocks = 4b x 8 row-groups(512 rows) x 8 j-eighths(512 j).
//   Partial O stored bf16 in C-frag-native layout [w][mt][nt][lane][r:4]
//   (coalesced 8B u2v stores, no write-allocate RMW).  K4: 8-way combine
//   reading that layout coalesced + softmax normalize + ELU.
// Fallback: if ws too small for partials, launch R7's monolithic k3.

#define ALPHA 0.2f
#define NN 4096
#define FD 128

typedef __attribute__((ext_vector_type(8))) short s8v;     // 8 x bf16 raw bits
typedef __attribute__((ext_vector_type(4))) float f4v;
typedef __attribute__((ext_vector_type(2))) unsigned int u2v;
typedef __attribute__((ext_vector_type(4))) unsigned int u4v;

__device__ __forceinline__ unsigned short f2bf(float x) {  // round-half-up
  return (unsigned short)((__float_as_uint(x) + 0x8000u) >> 16);
}
__device__ __forceinline__ float bf2f(unsigned short s) {
  return __uint_as_float(((unsigned)s) << 16);
}

// ---------------- K1: Wh + tiled WhT + s1/E/F (unchanged) ----------------
__global__ __launch_bounds__(256, 4) void k1_gemm(
    const float* __restrict__ h, const float* __restrict__ W,
    const float* __restrict__ a,
    unsigned short* __restrict__ WhTt,      // tiled [4][16][32][128][8] bf16
    float* __restrict__ s1g, float* __restrict__ Eg, float* __restrict__ Fg)
{
  __shared__ __align__(16) unsigned char wls[32768];
  const int tid = threadIdx.x;
  const int b = blockIdx.x >> 6;
  const int j0 = (blockIdx.x & 63) << 6;

#pragma unroll
  for (int it = 0; it < 16; ++it) {          // W -> swizzled bf16 W^T in LDS
    int cidx = it * 256 + tid;
    int i = cidx >> 5;
    int f0 = (cidx & 31) << 2;
    f4v v = *(const f4v*)(W + (size_t)cidx * 4);
#pragma unroll
    for (int e = 0; e < 4; ++e) {
      int f = f0 + e;
      int byte = f * 256 + (((i >> 3) ^ (f & 15)) << 4) + ((i & 7) << 1);
      *(unsigned short*)(wls + byte) = f2bf(v[e]);
    }
  }
  __syncthreads();

  const int w = tid >> 6, lane = tid & 63;
  const int quad = lane >> 4, lcol = lane & 15;
  const int jrow = j0 + 16 * w + lcol;

  f4v acc[8];
#pragma unroll
  for (int nt = 0; nt < 8; ++nt) acc[nt] = (f4v){0.f, 0.f, 0.f, 0.f};

#pragma unroll
  for (int kk = 0; kk < 4; ++kk) {
    const float* hp = h + (((size_t)(b * NN + jrow)) << 7) + (kk << 5) + (quad << 3);
    f4v v0 = *(const f4v*)hp;
    f4v v1 = *(const f4v*)(hp + 4);
    s8v af;
#pragma unroll
    for (int e = 0; e < 4; ++e) { af[e] = (short)f2bf(v0[e]); af[4+e] = (short)f2bf(v1[e]); }
#pragma unroll
    for (int nt = 0; nt < 8; ++nt) {
      int f = 16 * nt + lcol;
      int slot = ((kk << 2) + quad) ^ (f & 15);
      s8v bfr = *(const s8v*)(wls + (f << 8) + (slot << 4));
      acc[nt] = __builtin_amdgcn_mfma_f32_16x16x32_bf16(af, bfr, acc[nt], 0, 0, 0);
    }
  }

  float s1v[4] = {0,0,0,0}, s2v[4] = {0,0,0,0};
#pragma unroll
  for (int nt = 0; nt < 8; ++nt) {
    float a1 = a[16 * nt + lcol];
    float a2 = a[128 + 16 * nt + lcol];
#pragma unroll
    for (int r = 0; r < 4; ++r) { s1v[r] += acc[nt][r] * a1; s2v[r] += acc[nt][r] * a2; }
  }
#pragma unroll
  for (int r = 0; r < 4; ++r)
#pragma unroll
    for (int d = 1; d < 16; d <<= 1) {
      s1v[r] += __shfl_xor(s1v[r], d, 64);
      s2v[r] += __shfl_xor(s2v[r], d, 64);
    }
  if (lcol == 0) {
    int jb = b * NN + j0 + 16 * w + (quad << 2);
    *(f4v*)(s1g + jb) = (f4v){s1v[0], s1v[1], s1v[2], s1v[3]};
    f4v Ee, Ff;
#pragma unroll
    for (int r = 0; r < 4; ++r) {
      float d = s2v[r] - 8.0f;              // <= 0 given |s2| <= 8
      Ee[r] = __expf(d);
      Ff[r] = __expf(ALPHA * d);
    }
    *(f4v*)(Eg + jb) = Ee;
    *(f4v*)(Fg + jb) = Ff;
  }

  {
    const int c = j0 >> 8;
    const int octb = ((j0 & 255) >> 3) + 2 * w + (quad >> 1);
    const int eoff = (quad & 1) << 2;
#pragma unroll
    for (int nt = 0; nt < 8; ++nt) {
      int f = 16 * nt + lcol;
      unsigned u0 = __float_as_uint(acc[nt][0]) + 0x8000u;
      unsigned u1 = __float_as_uint(acc[nt][1]) + 0x8000u;
      unsigned u2 = __float_as_uint(acc[nt][2]) + 0x8000u;
      unsigned u3 = __float_as_uint(acc[nt][3]) + 0x8000u;
      u2v pk;
      pk[0] = (u0 >> 16) | (u1 & 0xFFFF0000u);
      pk[1] = (u2 >> 16) | (u3 & 0xFFFF0000u);
      size_t off = ((((size_t)(b * 16 + c) * 32 + octb) * 128 + f) << 3) + eoff;
      *(u2v*)(WhTt + off) = pk;
    }
  }
}

// ---------------- K3-split: partial P@Wh over a 512-j eighth ----------------
// grid 256 x 512 thr. blk: b=blk>>6, rg=(blk>>3)&7, jq=blk&7. Wave w owns
// rows [rg*512 + w*64, +64); all waves share the j-slice reads (L1 reuse).
// pO layout: [blk][w:8][mt:4][nt:8][lane:64][r:4] bf16 (coalesced u2v).
__global__ __launch_bounds__(512, 2) void k3_split(
    const unsigned short* __restrict__ WhTt,
    const float* __restrict__ s1g,
    const float* __restrict__ Eg,
    const float* __restrict__ Fg,
    unsigned short* __restrict__ pO,        // [256][65536] bf16
    float* __restrict__ pl)                 // [256][512] f32
{
  const int tid = threadIdx.x;
  const int w = tid >> 6, lane = tid & 63;
  const int quad = lane >> 4, lcol = lane & 15;
  const int blk = blockIdx.x;
  const int b = blk >> 6, rg = (blk >> 3) & 7, jq = blk & 7;
  const int irow0 = rg * 512 + w * 64;

  float rr[4];
#pragma unroll
  for (int mt = 0; mt < 4; ++mt) {
    float x = s1g[b * NN + irow0 + 16 * mt + lcol] + 8.0f;
    rr[mt] = __expf((ALPHA - 1.0f) * x);    // <= 1 (x >= 0)
  }

  f4v acc[4][8], accL[4];
#pragma unroll
  for (int mt = 0; mt < 4; ++mt) {
    accL[mt] = (f4v){0.f, 0.f, 0.f, 0.f};
#pragma unroll
    for (int nt = 0; nt < 8; ++nt) acc[mt][nt] = (f4v){0.f, 0.f, 0.f, 0.f};
  }
  s8v ones;
  {
    short o = (lcol == 0) ? (short)0x3F80 : (short)0;
#pragma unroll
    for (int t = 0; t < 8; ++t) ones[t] = o;
  }

  const unsigned short* whtb = WhTt + ((size_t)b << 19);
  const float* Egb = Eg + b * NN;
  const float* Fgb = Fg + b * NN;
  const int j0 = jq << 9;                   // 512-j window

  for (int sg = 0; sg < 4; ++sg) {          // 16 ksteps, barrier every 4
#pragma unroll
    for (int si = 0; si < 4; ++si) {
      const int s = (sg << 2) + si;
      const int jbase = j0 + (s << 5) + (quad << 3);
      const int og = jbase >> 3;            // global j-octet
      const unsigned short* tile =
          whtb + (((size_t)(og >> 5)) << 15) + ((og & 31) << 10);
      s8v bfr[8];
#pragma unroll
      for (int nt = 0; nt < 8; ++nt)
        bfr[nt] = *(const s8v*)(tile + (((nt << 4) + lcol) << 3));
      f4v Ea0 = *(const f4v*)(Egb + jbase);
      f4v Ea1 = *(const f4v*)(Egb + jbase + 4);
      f4v Fa0 = *(const f4v*)(Fgb + jbase);
      f4v Fa1 = *(const f4v*)(Fgb + jbase + 4);
      float Ev[8] = {Ea0[0], Ea0[1], Ea0[2], Ea0[3], Ea1[0], Ea1[1], Ea1[2], Ea1[3]};
      float Fv[8] = {Fa0[0], Fa0[1], Fa0[2], Fa0[3], Fa1[0], Fa1[1], Fa1[2], Fa1[3]};

      s8v af[4];
#pragma unroll
      for (int mt = 0; mt < 4; ++mt) {      // q = max(E, r*F), A-frag layout
        float R = rr[mt];
        u4v pk4;
#pragma unroll
        for (int t = 0; t < 8; t += 2) {
          float q0 = fmaxf(Ev[t], R * Fv[t]);
          float q1 = fmaxf(Ev[t + 1], R * Fv[t + 1]);
          unsigned u0 = __float_as_uint(q0) + 0x8000u;
          unsigned u1 = __float_as_uint(q1) + 0x8000u;
          pk4[t >> 1] = __builtin_amdgcn_perm(u1, u0, 0x07060302);
        }
        af[mt] = __builtin_bit_cast(s8v, pk4);
      }
#pragma unroll
      for (int nt = 0; nt < 8; ++nt)
#pragma unroll
        for (int mt = 0; mt < 4; ++mt)
          acc[mt][nt] = __builtin_amdgcn_mfma_f32_16x16x32_bf16(af[mt], bfr[nt], acc[mt][nt], 0, 0, 0);
#pragma unroll
      for (int mt = 0; mt < 4; ++mt)
        accL[mt] = __builtin_amdgcn_mfma_f32_16x16x32_bf16(af[mt], ones, accL[mt], 0, 0, 0);
    }
    __syncthreads();                        // keep waves in L1 reuse window
  }

  // partial stores, C-frag-native coalesced layout
  if (lcol == 0) {
#pragma unroll
    for (int mt = 0; mt < 4; ++mt)
#pragma unroll
      for (int r = 0; r < 4; ++r)
        pl[(size_t)blk * 512 + w * 64 + 16 * mt + (quad << 2) + r] = accL[mt][r];
  }
  unsigned short* po = pO + (size_t)blk * 65536;
#pragma unroll
  for (int mt = 0; mt < 4; ++mt)
#pragma unroll
    for (int nt = 0; nt < 8; ++nt) {
      unsigned u0 = __float_as_uint(acc[mt][nt][0]) + 0x8000u;
      unsigned u1 = __float_as_uint(acc[mt][nt][1]) + 0x8000u;
      unsigned u2 = __float_as_uint(acc[mt][nt][2]) + 0x8000u;
      unsigned u3 = __float_as_uint(acc[mt][nt][3]) + 0x8000u;
      u2v pk;
      pk[0] = (u0 >> 16) | (u1 & 0xFFFF0000u);
      pk[1] = (u2 >> 16) | (u3 & 0xFFFF0000u);
      int off = ((((w << 2) + mt) << 3) + nt) * 256 + (lane << 2);
      *(u2v*)(po + off) = pk;
    }
}

// ---------------- K4: 8-way combine + softmax normalize + ELU ----------------
// grid 256 x 256 thr. blk = (b*8 + rg)*8 + w; thread: mt = tid>>6, lane rest.
// Reads pO coalesced in its native layout; writes out f32 coalesced.
__global__ __launch_bounds__(256) void k4_comb(
    const unsigned short* __restrict__ pO, const float* __restrict__ pl,
    float* __restrict__ out)
{
  const int tid = threadIdx.x, blk = blockIdx.x;
  const int b = blk >> 6, rg = (blk >> 3) & 7, w = blk & 7;
  const int mt = tid >> 6, lane = tid & 63;
  const int quad = lane >> 4, lcol = lane & 15;
  const int pbase = (b << 6) | (rg << 3);   // + jq

  // l for this thread's 4 rows
  float il[4];
#pragma unroll
  for (int r = 0; r < 4; ++r) {
    int rowloc = w * 64 + 16 * mt + (quad << 2) + r;
    float l = 0.f;
#pragma unroll
    for (int q = 0; q < 8; ++q) l += pl[(size_t)(pbase + q) * 512 + rowloc];
    il[r] = 1.0f / l;
  }

  const size_t rowg0 = ((size_t)b * NN + rg * 512 + w * 64 + 16 * mt + (quad << 2));
#pragma unroll
  for (int nt = 0; nt < 8; ++nt) {
    const int off = ((((w << 2) + mt) << 3) + nt) * 256 + (lane << 2);
    float s0 = 0.f, s1 = 0.f, s2 = 0.f, s3 = 0.f;
#pragma unroll
    for (int q = 0; q < 8; ++q) {
      u2v pk = *(const u2v*)(pO + (size_t)(pbase + q) * 65536 + off);
      s0 += __uint_as_float(pk[0] << 16);
      s1 += __uint_as_float(pk[0] & 0xFFFF0000u);
      s2 += __uint_as_float(pk[1] << 16);
      s3 += __uint_as_float(pk[1] & 0xFFFF0000u);
    }
    float v[4] = {s0 * il[0], s1 * il[1], s2 * il[2], s3 * il[3]};
#pragma unroll
    for (int r = 0; r < 4; ++r) {
      float x = v[r];
      x = x > 0.f ? x : (__expf(x) - 1.f);  // elu
      out[(rowg0 + r) * 128 + (nt << 4) + lcol] = x;
    }
  }
}

// ---------------- K3-mono (R7 fallback, verbatim) ----------------
__global__ __launch_bounds__(512, 2) void k3_mono(
    const unsigned short* __restrict__ WhTt,
    const float* __restrict__ s1g,
    const float* __restrict__ Eg,
    const float* __restrict__ Fg,
    float* __restrict__ out)
{
  __shared__ __align__(16) unsigned char smem[33024];
  const int tid = threadIdx.x;
  const int kp = tid >> 6, lane = tid & 63;
  const int quad = lane >> 4, lcol = lane & 15;
  const int b = (blockIdx.x & 7) >> 1;
  const int i0 = ((((blockIdx.x & 1) << 5) | (blockIdx.x >> 3))) << 6;
  const int c0 = (blockIdx.x >> 3) & 15;
  const int oct = (kp << 2) + quad;

  float Ar[4], Br[4];
#pragma unroll
  for (int mt = 0; mt < 4; ++mt) {
    float x = s1g[b * NN + i0 + 16 * mt + lcol] + 8.0f;
    float m = fmaxf(x, ALPHA * x);
    Ar[mt] = __expf(x - m);
    Br[mt] = __expf(ALPHA * x - m);
  }

  f4v acc[4][8], accL[4];
#pragma unroll
  for (int mt = 0; mt < 4; ++mt) {
    accL[mt] = (f4v){0.f, 0.f, 0.f, 0.f};
#pragma unroll
    for (int nt = 0; nt < 8; ++nt) acc[mt][nt] = (f4v){0.f, 0.f, 0.f, 0.f};
  }
  s8v ones;
  {
    short o = (lcol == 0) ? (short)0x3F80 : (short)0;
#pragma unroll
    for (int t = 0; t < 8; ++t) ones[t] = o;
  }

  const unsigned short* whtb = WhTt + ((size_t)b << 19);
  const float* Egb = Eg + b * NN;
  const float* Fgb = Fg + b * NN;
  const int jw = oct << 3;

  f4v Ec0 = *(const f4v*)(Egb + (c0 << 8) + jw);
  f4v Ec1 = *(const f4v*)(Egb + (c0 << 8) + jw + 4);
  f4v Fc0 = *(const f4v*)(Fgb + (c0 << 8) + jw);
  f4v Fc1 = *(const f4v*)(Fgb + (c0 << 8) + jw + 4);

  for (int cc = 0; cc < 16; ++cc) {
    const int c = (cc + c0) & 15;
    const unsigned short* tile = whtb + ((size_t)c << 15) + (oct << 10);
    s8v bfr[8];
#pragma unroll
    for (int nt = 0; nt < 8; ++nt)
      bfr[nt] = *(const s8v*)(tile + (((nt << 4) + lcol) << 3));

    f4v En0, En1, Fn0, Fn1;
    if (cc < 15) {
      int jg = (((cc + 1 + c0) & 15) << 8) + jw;
      En0 = *(const f4v*)(Egb + jg); En1 = *(const f4v*)(Egb + jg + 4);
      Fn0 = *(const f4v*)(Fgb + jg); Fn1 = *(const f4v*)(Fgb + jg + 4);
    }

    float Ev[8] = {Ec0[0], Ec0[1], Ec0[2], Ec0[3], Ec1[0], Ec1[1], Ec1[2], Ec1[3]};
    float Fv[8] = {Fc0[0], Fc0[1], Fc0[2], Fc0[3], Fc1[0], Fc1[1], Fc1[2], Fc1[3]};

    s8v af[4];
#pragma unroll
    for (int mt = 0; mt < 4; ++mt) {
      float A = Ar[mt], Bc = Br[mt];
      u4v pk4;
#pragma unroll
      for (int t = 0; t < 8; t += 2) {
        float p0 = fmaxf(A * Ev[t], Bc * Fv[t]);
        float p1 = fmaxf(A * Ev[t + 1], Bc * Fv[t + 1]);
        unsigned u0 = __float_as_uint(p0) + 0x8000u;
        unsigned u1 = __float_as_uint(p1) + 0x8000u;
        pk4[t >> 1] = __builtin_amdgcn_perm(u1, u0, 0x07060302);
      }
      af[mt] = __builtin_bit_cast(s8v, pk4);
    }
#pragma unroll
    for (int nt = 0; nt < 8; ++nt)
#pragma unroll
      for (int mt = 0; mt < 4; ++mt)
        acc[mt][nt] = __builtin_amdgcn_mfma_f32_16x16x32_bf16(af[mt], bfr[nt], acc[mt][nt], 0, 0, 0);
#pragma unroll
    for (int mt = 0; mt < 4; ++mt)
      accL[mt] = __builtin_amdgcn_mfma_f32_16x16x32_bf16(af[mt], ones, accL[mt], 0, 0, 0);

    Ec0 = En0; Ec1 = En1; Fc0 = Fn0; Fc1 = Fn1;
  }

  float* hsum = (float*)smem;
  float* l_red = (float*)(smem + 32768);
#pragma unroll
  for (int t = 0; t < 4; ++t)
    *(f4v*)(hsum + tid * 16 + t * 4) = (f4v){0.f, 0.f, 0.f, 0.f};
  if (tid < 64) l_red[tid] = 0.f;
  __syncthreads();

#pragma unroll
  for (int mt = 0; mt < 4; ++mt) {
    if (lcol == 0) {
#pragma unroll
      for (int r = 0; r < 4; ++r)
        atomicAdd(&l_red[16 * mt + (quad << 2) + r], accL[mt][r]);
    }
#pragma unroll
    for (int nt = 0; nt < 8; ++nt)
#pragma unroll
      for (int r = 0; r < 4; ++r) {
        int row = 16 * mt + (quad << 2) + r;
        int f = (nt << 4) + lcol;
        int fx = (f + (quad << 3)) & 127;
        atomicAdd(&hsum[(row << 7) + fx], acc[mt][nt][r]);
      }
  }
  __syncthreads();

  {
    int r = tid >> 3;
    int f0 = (tid & 7) << 4;
    int off = ((r >> 2) & 3) << 3;
    float il = 1.0f / l_red[r];
    size_t o = (((size_t)b * NN + i0 + r) << 7) + f0;
#pragma unroll
    for (int t = 0; t < 4; ++t) {
      int fx = (f0 + 4 * t + off) & 127;
      f4v v = *(const f4v*)(hsum + (r << 7) + fx);
      f4v ov;
#pragma unroll
      for (int e = 0; e < 4; ++e) {
        float x = v[e] * il;
        ov[e] = x > 0.f ? x : (__expf(x) - 1.f);
      }
      *(f4v*)(out + o + 4 * t) = ov;
    }
  }
}

extern "C" void kernel_launch(void* const* d_in, const int* in_sizes, int n_in,
                              void* d_out, int out_size, void* d_ws, size_t ws_size,
                              hipStream_t stream) {
  const float* h = (const float*)d_in[0];
  const float* W = (const float*)d_in[1];
  const float* a = (const float*)d_in[2];
  float* out = (float*)d_out;
  unsigned char* ws = (unsigned char*)d_ws;

  unsigned short* WhTt = (unsigned short*)ws;             // 4 MB tiled bf16
  float* s1g = (float*)(ws + 4194304);                    // 64 KB
  float* Eg  = (float*)(ws + 4259840);                    // 64 KB
  float* Fg  = (float*)(ws + 4325376);                    // 64 KB
  unsigned short* pO = (unsigned short*)(ws + 4390912);   // 33.6 MB bf16
  float* pl = (float*)(ws + 37945344);                    // 512 KB
  const size_t NEED_SPLIT = 38469632;
  const size_t NEED_MONO = 4390912;
  if (ws_size < NEED_MONO) return;  // clean absmax-fail => ws too small

  hipLaunchKernelGGL(k1_gemm, dim3(256), dim3(256), 0, stream,
                     h, W, a, WhTt, s1g, Eg, Fg);
  if (ws_size >= NEED_SPLIT) {
    hipLaunchKernelGGL(k3_split, dim3(256), dim3(512), 0, stream,
                       WhTt, s1g, Eg, Fg, pO, pl);
    hipLaunchKernelGGL(k4_comb, dim3(256), dim3(256), 0, stream,
                       pO, pl, out);
  } else {
    hipLaunchKernelGGL(k3_mono, dim3(256), dim3(512), 0, stream,
                       WhTt, s1g, Eg, Fg, out);
  }
}

// Round 12
// 106.529 us; speedup vs baseline: 4.7441x; 1.2467x over previous
//
#include <hip/hip_runtime.h>
#include <hip/hip_bf16.h>

// GraphAttentionLayer on MI355X. fp32 I/O, bf16 MFMA internally.
// e = LR(s1_i + s2_j), softmax_j, out = elu(attn @ Wh).
// Scale-free scores: q_ij = max(E_j, r_i*F_j); E=exp(s2-8), F=exp(a(s2-8)),
//   r_i = exp((a-1)(s1_i+8));  O_i = sum_j q Wh / sum_j q.
// K1: Wh MFMA -> tiled WhT [b][c:16][oct:32][f:128][jo:8] bf16 + s1,E,F.
// K3-split v3: 256 blocks = 4b x 8rg(512 rows) x 8jq(512 j). Per 32-j kstep
//   the block's shared 8KB B-tile is staged ONCE into LDS via EXPLICIT
//   global_load_dwordx4 -> ds_write_b128 (no global_load_lds — R11's direct-
//   to-LDS variant faulted; this keeps the same vmem-instr math: 8 wave
//   instrs/kstep vs 96 redundant direct loads at ~85cyc/instr per CU).
//   Register double-buffer hides load latency across the barrier. E/F 4KB
//   window staged once. Epilogue: pO C-frag coalesced bf16 + pl (R10).
// K4: 8-way combine + normalize + ELU (R10). Fallback: monolithic k3.

#define ALPHA 0.2f
#define NN 4096
#define FD 128

typedef __attribute__((ext_vector_type(8))) short s8v;     // 8 x bf16 raw bits
typedef __attribute__((ext_vector_type(4))) float f4v;
typedef __attribute__((ext_vector_type(2))) unsigned int u2v;
typedef __attribute__((ext_vector_type(4))) unsigned int u4v;

__device__ __forceinline__ unsigned short f2bf(float x) {  // round-half-up
  return (unsigned short)((__float_as_uint(x) + 0x8000u) >> 16);
}
__device__ __forceinline__ float bf2f(unsigned short s) {
  return __uint_as_float(((unsigned)s) << 16);
}

// ---------------- K1: Wh + tiled WhT + s1/E/F (unchanged) ----------------
__global__ __launch_bounds__(256, 4) void k1_gemm(
    const float* __restrict__ h, const float* __restrict__ W,
    const float* __restrict__ a,
    unsigned short* __restrict__ WhTt,      // tiled [4][16][32][128][8] bf16
    float* __restrict__ s1g, float* __restrict__ Eg, float* __restrict__ Fg)
{
  __shared__ __align__(16) unsigned char wls[32768];
  const int tid = threadIdx.x;
  const int b = blockIdx.x >> 6;
  const int j0 = (blockIdx.x & 63) << 6;

#pragma unroll
  for (int it = 0; it < 16; ++it) {          // W -> swizzled bf16 W^T in LDS
    int cidx = it * 256 + tid;
    int i = cidx >> 5;
    int f0 = (cidx & 31) << 2;
    f4v v = *(const f4v*)(W + (size_t)cidx * 4);
#pragma unroll
    for (int e = 0; e < 4; ++e) {
      int f = f0 + e;
      int byte = f * 256 + (((i >> 3) ^ (f & 15)) << 4) + ((i & 7) << 1);
      *(unsigned short*)(wls + byte) = f2bf(v[e]);
    }
  }
  __syncthreads();

  const int w = tid >> 6, lane = tid & 63;
  const int quad = lane >> 4, lcol = lane & 15;
  const int jrow = j0 + 16 * w + lcol;

  f4v acc[8];
#pragma unroll
  for (int nt = 0; nt < 8; ++nt) acc[nt] = (f4v){0.f, 0.f, 0.f, 0.f};

#pragma unroll
  for (int kk = 0; kk < 4; ++kk) {
    const float* hp = h + (((size_t)(b * NN + jrow)) << 7) + (kk << 5) + (quad << 3);
    f4v v0 = *(const f4v*)hp;
    f4v v1 = *(const f4v*)(hp + 4);
    s8v af;
#pragma unroll
    for (int e = 0; e < 4; ++e) { af[e] = (short)f2bf(v0[e]); af[4+e] = (short)f2bf(v1[e]); }
#pragma unroll
    for (int nt = 0; nt < 8; ++nt) {
      int f = 16 * nt + lcol;
      int slot = ((kk << 2) + quad) ^ (f & 15);
      s8v bfr = *(const s8v*)(wls + (f << 8) + (slot << 4));
      acc[nt] = __builtin_amdgcn_mfma_f32_16x16x32_bf16(af, bfr, acc[nt], 0, 0, 0);
    }
  }

  float s1v[4] = {0,0,0,0}, s2v[4] = {0,0,0,0};
#pragma unroll
  for (int nt = 0; nt < 8; ++nt) {
    float a1 = a[16 * nt + lcol];
    float a2 = a[128 + 16 * nt + lcol];
#pragma unroll
    for (int r = 0; r < 4; ++r) { s1v[r] += acc[nt][r] * a1; s2v[r] += acc[nt][r] * a2; }
  }
#pragma unroll
  for (int r = 0; r < 4; ++r)
#pragma unroll
    for (int d = 1; d < 16; d <<= 1) {
      s1v[r] += __shfl_xor(s1v[r], d, 64);
      s2v[r] += __shfl_xor(s2v[r], d, 64);
    }
  if (lcol == 0) {
    int jb = b * NN + j0 + 16 * w + (quad << 2);
    *(f4v*)(s1g + jb) = (f4v){s1v[0], s1v[1], s1v[2], s1v[3]};
    f4v Ee, Ff;
#pragma unroll
    for (int r = 0; r < 4; ++r) {
      float d = s2v[r] - 8.0f;              // <= 0 given |s2| <= 8
      Ee[r] = __expf(d);
      Ff[r] = __expf(ALPHA * d);
    }
    *(f4v*)(Eg + jb) = Ee;
    *(f4v*)(Fg + jb) = Ff;
  }

  {
    const int c = j0 >> 8;
    const int octb = ((j0 & 255) >> 3) + 2 * w + (quad >> 1);
    const int eoff = (quad & 1) << 2;
#pragma unroll
    for (int nt = 0; nt < 8; ++nt) {
      int f = 16 * nt + lcol;
      unsigned u0 = __float_as_uint(acc[nt][0]) + 0x8000u;
      unsigned u1 = __float_as_uint(acc[nt][1]) + 0x8000u;
      unsigned u2 = __float_as_uint(acc[nt][2]) + 0x8000u;
      unsigned u3 = __float_as_uint(acc[nt][3]) + 0x8000u;
      u2v pk;
      pk[0] = (u0 >> 16) | (u1 & 0xFFFF0000u);
      pk[1] = (u2 >> 16) | (u3 & 0xFFFF0000u);
      size_t off = ((((size_t)(b * 16 + c) * 32 + octb) * 128 + f) << 3) + eoff;
      *(u2v*)(WhTt + off) = pk;
    }
  }
}

// ---------------- K3-split v3: LDS-staged partial P@Wh (no gl2lds) --------
// grid 256 x 512 thr. blk: b=blk>>6, rg=(blk>>3)&7, jq=blk&7. Wave w owns
// rows [rg*512 + w*64, +64). 8KB/kstep B-tile staged via regs + ds_write.
// LDS: [0,8K) buf0 | [8K,16K) buf1 | [16K,18K) E window | [18K,20K) F.
__global__ __launch_bounds__(512, 2) void k3_split(
    const unsigned short* __restrict__ WhTt,
    const float* __restrict__ s1g,
    const float* __restrict__ Eg,
    const float* __restrict__ Fg,
    unsigned short* __restrict__ pO,        // [256][65536] bf16
    float* __restrict__ pl)                 // [256][512] f32
{
  __shared__ __align__(16) unsigned char smem[20480];
  const int tid = threadIdx.x;
  const int w = tid >> 6, lane = tid & 63;
  const int quad = lane >> 4, lcol = lane & 15;
  const int blk = blockIdx.x;
  const int b = blk >> 6, rg = (blk >> 3) & 7, jq = blk & 7;
  const int irow0 = rg * 512 + w * 64;

  const unsigned short* whtb = WhTt + ((size_t)b << 19);
  const float* Egb = Eg + b * NN + (jq << 9);
  const float* Fgb = Fg + b * NN + (jq << 9);

  float rr[4];
#pragma unroll
  for (int mt = 0; mt < 4; ++mt) {
    float x = s1g[b * NN + irow0 + 16 * mt + lcol] + 8.0f;
    rr[mt] = __expf((ALPHA - 1.0f) * x);    // <= 1 (x >= 0)
  }

  // E/F window: 512 + 512 floats, staged once (threads 0..255, 16B each)
  if (tid < 128) {
    f4v v = *(const f4v*)(Egb + tid * 4);
    *(f4v*)(smem + 16384 + tid * 16) = v;
  } else if (tid < 256) {
    f4v v = *(const f4v*)(Fgb + (tid - 128) * 4);
    *(f4v*)(smem + 18432 + (tid - 128) * 16) = v;
  }

  // B-tile for kstep s: 4 contiguous octets = 8KB (never crosses a c-tile)
  auto tilePtr = [&](int s) -> const unsigned short* {
    int og0 = (jq << 6) + (s << 2);
    return whtb + (((size_t)(og0 >> 5)) << 15) + ((og0 & 31) << 10);
  };
  {
    u4v t0 = *(const u4v*)(tilePtr(0) + tid * 8);
    *(u4v*)(smem + tid * 16) = t0;          // buf0
  }

  f4v acc[4][8], accL[4];
#pragma unroll
  for (int mt = 0; mt < 4; ++mt) {
    accL[mt] = (f4v){0.f, 0.f, 0.f, 0.f};
#pragma unroll
    for (int nt = 0; nt < 8; ++nt) acc[mt][nt] = (f4v){0.f, 0.f, 0.f, 0.f};
  }
  s8v ones;
  {
    short o = (lcol == 0) ? (short)0x3F80 : (short)0;
#pragma unroll
    for (int t = 0; t < 8; ++t) ones[t] = o;
  }

  const float* EFb = (const float*)(smem + 16384);

  for (int s = 0; s < 16; ++s) {            // 16 ksteps x 32 j
    __syncthreads();                        // tile s + EF resident; prev reads done
    u4v tn;
    if (s < 15) tn = *(const u4v*)(tilePtr(s + 1) + tid * 8);  // reg prefetch
    const unsigned char* buf = smem + ((s & 1) << 13);

    const int jloc = (s << 5) + (quad << 3);
    f4v Ea0 = *(const f4v*)(EFb + jloc);
    f4v Ea1 = *(const f4v*)(EFb + jloc + 4);
    f4v Fa0 = *(const f4v*)(EFb + 512 + jloc);
    f4v Fa1 = *(const f4v*)(EFb + 512 + jloc + 4);
    float Ev[8] = {Ea0[0], Ea0[1], Ea0[2], Ea0[3], Ea1[0], Ea1[1], Ea1[2], Ea1[3]};
    float Fv[8] = {Fa0[0], Fa0[1], Fa0[2], Fa0[3], Fa1[0], Fa1[1], Fa1[2], Fa1[3]};

    s8v bfr[8];
#pragma unroll
    for (int nt = 0; nt < 8; ++nt) {        // B-frag: oct=quad, row f
      int f = (nt << 4) + lcol;
      bfr[nt] = *(const s8v*)(buf + (quad << 11) + (f << 4));
    }

    s8v af[4];
#pragma unroll
    for (int mt = 0; mt < 4; ++mt) {        // q = max(E, r*F), A-frag layout
      float R = rr[mt];
      u4v pk4;
#pragma unroll
      for (int t = 0; t < 8; t += 2) {
        float q0 = fmaxf(Ev[t], R * Fv[t]);
        float q1 = fmaxf(Ev[t + 1], R * Fv[t + 1]);
        unsigned u0 = __float_as_uint(q0) + 0x8000u;
        unsigned u1 = __float_as_uint(q1) + 0x8000u;
        pk4[t >> 1] = __builtin_amdgcn_perm(u1, u0, 0x07060302);
      }
      af[mt] = __builtin_bit_cast(s8v, pk4);
    }
#pragma unroll
    for (int nt = 0; nt < 8; ++nt)
#pragma unroll
      for (int mt = 0; mt < 4; ++mt)
        acc[mt][nt] = __builtin_amdgcn_mfma_f32_16x16x32_bf16(af[mt], bfr[nt], acc[mt][nt], 0, 0, 0);
#pragma unroll
    for (int mt = 0; mt < 4; ++mt)
      accL[mt] = __builtin_amdgcn_mfma_f32_16x16x32_bf16(af[mt], ones, accL[mt], 0, 0, 0);

    if (s < 15)                             // write prefetched tile s+1
      *(u4v*)(smem + (((s + 1) & 1) << 13) + tid * 16) = tn;
  }

  // partial stores, C-frag-native coalesced layout (R10)
  if (lcol == 0) {
#pragma unroll
    for (int mt = 0; mt < 4; ++mt)
#pragma unroll
      for (int r = 0; r < 4; ++r)
        pl[(size_t)blk * 512 + w * 64 + 16 * mt + (quad << 2) + r] = accL[mt][r];
  }
  unsigned short* po = pO + (size_t)blk * 65536;
#pragma unroll
  for (int mt = 0; mt < 4; ++mt)
#pragma unroll
    for (int nt = 0; nt < 8; ++nt) {
      unsigned u0 = __float_as_uint(acc[mt][nt][0]) + 0x8000u;
      unsigned u1 = __float_as_uint(acc[mt][nt][1]) + 0x8000u;
      unsigned u2 = __float_as_uint(acc[mt][nt][2]) + 0x8000u;
      unsigned u3 = __float_as_uint(acc[mt][nt][3]) + 0x8000u;
      u2v pk;
      pk[0] = (u0 >> 16) | (u1 & 0xFFFF0000u);
      pk[1] = (u2 >> 16) | (u3 & 0xFFFF0000u);
      int off = ((((w << 2) + mt) << 3) + nt) * 256 + (lane << 2);
      *(u2v*)(po + off) = pk;
    }
}

// ---------------- K4: 8-way combine + softmax normalize + ELU (R10) --------
__global__ __launch_bounds__(256) void k4_comb(
    const unsigned short* __restrict__ pO, const float* __restrict__ pl,
    float* __restrict__ out)
{
  const int tid = threadIdx.x, blk = blockIdx.x;
  const int b = blk >> 6, rg = (blk >> 3) & 7, w = blk & 7;
  const int mt = tid >> 6, lane = tid & 63;
  const int quad = lane >> 4, lcol = lane & 15;
  const int pbase = (b << 6) | (rg << 3);

  float il[4];
#pragma unroll
  for (int r = 0; r < 4; ++r) {
    int rowloc = w * 64 + 16 * mt + (quad << 2) + r;
    float l = 0.f;
#pragma unroll
    for (int q = 0; q < 8; ++q) l += pl[(size_t)(pbase + q) * 512 + rowloc];
    il[r] = 1.0f / l;
  }

  const size_t rowg0 = ((size_t)b * NN + rg * 512 + w * 64 + 16 * mt + (quad << 2));
#pragma unroll
  for (int nt = 0; nt < 8; ++nt) {
    const int off = ((((w << 2) + mt) << 3) + nt) * 256 + (lane << 2);
    float s0 = 0.f, s1 = 0.f, s2 = 0.f, s3 = 0.f;
#pragma unroll
    for (int q = 0; q < 8; ++q) {
      u2v pk = *(const u2v*)(pO + (size_t)(pbase + q) * 65536 + off);
      s0 += __uint_as_float(pk[0] << 16);
      s1 += __uint_as_float(pk[0] & 0xFFFF0000u);
      s2 += __uint_as_float(pk[1] << 16);
      s3 += __uint_as_float(pk[1] & 0xFFFF0000u);
    }
    float v[4] = {s0 * il[0], s1 * il[1], s2 * il[2], s3 * il[3]};
#pragma unroll
    for (int r = 0; r < 4; ++r) {
      float x = v[r];
      x = x > 0.f ? x : (__expf(x) - 1.f);  // elu
      out[(rowg0 + r) * 128 + (nt << 4) + lcol] = x;
    }
  }
}

// ---------------- K3-mono (fallback, verbatim) ----------------
__global__ __launch_bounds__(512, 2) void k3_mono(
    const unsigned short* __restrict__ WhTt,
    const float* __restrict__ s1g,
    const float* __restrict__ Eg,
    const float* __restrict__ Fg,
    float* __restrict__ out)
{
  __shared__ __align__(16) unsigned char smem[33024];
  const int tid = threadIdx.x;
  const int kp = tid >> 6, lane = tid & 63;
  const int quad = lane >> 4, lcol = lane & 15;
  const int b = (blockIdx.x & 7) >> 1;
  const int i0 = ((((blockIdx.x & 1) << 5) | (blockIdx.x >> 3))) << 6;
  const int c0 = (blockIdx.x >> 3) & 15;
  const int oct = (kp << 2) + quad;

  float Ar[4], Br[4];
#pragma unroll
  for (int mt = 0; mt < 4; ++mt) {
    float x = s1g[b * NN + i0 + 16 * mt + lcol] + 8.0f;
    float m = fmaxf(x, ALPHA * x);
    Ar[mt] = __expf(x - m);
    Br[mt] = __expf(ALPHA * x - m);
  }

  f4v acc[4][8], accL[4];
#pragma unroll
  for (int mt = 0; mt < 4; ++mt) {
    accL[mt] = (f4v){0.f, 0.f, 0.f, 0.f};
#pragma unroll
    for (int nt = 0; nt < 8; ++nt) acc[mt][nt] = (f4v){0.f, 0.f, 0.f, 0.f};
  }
  s8v ones;
  {
    short o = (lcol == 0) ? (short)0x3F80 : (short)0;
#pragma unroll
    for (int t = 0; t < 8; ++t) ones[t] = o;
  }

  const unsigned short* whtb = WhTt + ((size_t)b << 19);
  const float* Egb = Eg + b * NN;
  const float* Fgb = Fg + b * NN;
  const int jw = oct << 3;

  f4v Ec0 = *(const f4v*)(Egb + (c0 << 8) + jw);
  f4v Ec1 = *(const f4v*)(Egb + (c0 << 8) + jw + 4);
  f4v Fc0 = *(const f4v*)(Fgb + (c0 << 8) + jw);
  f4v Fc1 = *(const f4v*)(Fgb + (c0 << 8) + jw + 4);

  for (int cc = 0; cc < 16; ++cc) {
    const int c = (cc + c0) & 15;
    const unsigned short* tile = whtb + ((size_t)c << 15) + (oct << 10);
    s8v bfr[8];
#pragma unroll
    for (int nt = 0; nt < 8; ++nt)
      bfr[nt] = *(const s8v*)(tile + (((nt << 4) + lcol) << 3));

    f4v En0, En1, Fn0, Fn1;
    if (cc < 15) {
      int jg = (((cc + 1 + c0) & 15) << 8) + jw;
      En0 = *(const f4v*)(Egb + jg); En1 = *(const f4v*)(Egb + jg + 4);
      Fn0 = *(const f4v*)(Fgb + jg); Fn1 = *(const f4v*)(Fgb + jg + 4);
    }

    float Ev[8] = {Ec0[0], Ec0[1], Ec0[2], Ec0[3], Ec1[0], Ec1[1], Ec1[2], Ec1[3]};
    float Fv[8] = {Fc0[0], Fc0[1], Fc0[2], Fc0[3], Fc1[0], Fc1[1], Fc1[2], Fc1[3]};

    s8v af[4];
#pragma unroll
    for (int mt = 0; mt < 4; ++mt) {
      float A = Ar[mt], Bc = Br[mt];
      u4v pk4;
#pragma unroll
      for (int t = 0; t < 8; t += 2) {
        float p0 = fmaxf(A * Ev[t], Bc * Fv[t]);
        float p1 = fmaxf(A * Ev[t + 1], Bc * Fv[t + 1]);
        unsigned u0 = __float_as_uint(p0) + 0x8000u;
        unsigned u1 = __float_as_uint(p1) + 0x8000u;
        pk4[t >> 1] = __builtin_amdgcn_perm(u1, u0, 0x07060302);
      }
      af[mt] = __builtin_bit_cast(s8v, pk4);
    }
#pragma unroll
    for (int nt = 0; nt < 8; ++nt)
#pragma unroll
      for (int mt = 0; mt < 4; ++mt)
        acc[mt][nt] = __builtin_amdgcn_mfma_f32_16x16x32_bf16(af[mt], bfr[nt], acc[mt][nt], 0, 0, 0);
#pragma unroll
    for (int mt = 0; mt < 4; ++mt)
      accL[mt] = __builtin_amdgcn_mfma_f32_16x16x32_bf16(af[mt], ones, accL[mt], 0, 0, 0);

    Ec0 = En0; Ec1 = En1; Fc0 = Fn0; Fc1 = Fn1;
  }

  float* hsum = (float*)smem;
  float* l_red = (float*)(smem + 32768);
#pragma unroll
  for (int t = 0; t < 4; ++t)
    *(f4v*)(hsum + tid * 16 + t * 4) = (f4v){0.f, 0.f, 0.f, 0.f};
  if (tid < 64) l_red[tid] = 0.f;
  __syncthreads();

#pragma unroll
  for (int mt = 0; mt < 4; ++mt) {
    if (lcol == 0) {
#pragma unroll
      for (int r = 0; r < 4; ++r)
        atomicAdd(&l_red[16 * mt + (quad << 2) + r], accL[mt][r]);
    }
#pragma unroll
    for (int nt = 0; nt < 8; ++nt)
#pragma unroll
      for (int r = 0; r < 4; ++r) {
        int row = 16 * mt + (quad << 2) + r;
        int f = (nt << 4) + lcol;
        int fx = (f + (quad << 3)) & 127;
        atomicAdd(&hsum[(row << 7) + fx], acc[mt][nt][r]);
      }
  }
  __syncthreads();

  {
    int r = tid >> 3;
    int f0 = (tid & 7) << 4;
    int off = ((r >> 2) & 3) << 3;
    float il = 1.0f / l_red[r];
    size_t o = (((size_t)b * NN + i0 + r) << 7) + f0;
#pragma unroll
    for (int t = 0; t < 4; ++t) {
      int fx = (f0 + 4 * t + off) & 127;
      f4v v = *(const f4v*)(hsum + (r << 7) + fx);
      f4v ov;
#pragma unroll
      for (int e = 0; e < 4; ++e) {
        float x = v[e] * il;
        ov[e] = x > 0.f ? x : (__expf(x) - 1.f);
      }
      *(f4v*)(out + o + 4 * t) = ov;
    }
  }
}

extern "C" void kernel_launch(void* const* d_in, const int* in_sizes, int n_in,
                              void* d_out, int out_size, void* d_ws, size_t ws_size,
                              hipStream_t stream) {
  const float* h = (const float*)d_in[0];
  const float* W = (const float*)d_in[1];
  const float* a = (const float*)d_in[2];
  float* out = (float*)d_out;
  unsigned char* ws = (unsigned char*)d_ws;

  unsigned short* WhTt = (unsigned short*)ws;             // 4 MB tiled bf16
  float* s1g = (float*)(ws + 4194304);                    // 64 KB
  float* Eg  = (float*)(ws + 4259840);                    // 64 KB
  float* Fg  = (float*)(ws + 4325376);                    // 64 KB
  unsigned short* pO = (unsigned short*)(ws + 4390912);   // 33.6 MB bf16
  float* pl = (float*)(ws + 37945344);                    // 512 KB
  const size_t NEED_SPLIT = 38469632;
  const size_t NEED_MONO = 4390912;
  if (ws_size < NEED_MONO) return;  // clean absmax-fail => ws too small

  hipLaunchKernelGGL(k1_gemm, dim3(256), dim3(256), 0, stream,
                     h, W, a, WhTt, s1g, Eg, Fg);
  if (ws_size >= NEED_SPLIT) {
    hipLaunchKernelGGL(k3_split, dim3(256), dim3(512), 0, stream,
                       WhTt, s1g, Eg, Fg, pO, pl);
    hipLaunchKernelGGL(k4_comb, dim3(256), dim3(256), 0, stream,
                       pO, pl, out);
  } else {
    hipLaunchKernelGGL(k3_mono, dim3(256), dim3(512), 0, stream,
                       WhTt, s1g, Eg, Fg, out);
  }
}